// Round 6
// baseline (166.091 us; speedup 1.0000x reference)
//
#include <hip/hip_runtime.h>
#include <hip/hip_fp16.h>

// ---------------- bicubic helpers (A = -0.75, torch) ----------------
__device__ __forceinline__ float cc1(float x) {
    return (1.25f * x - 2.25f) * x * x + 1.0f;
}
__device__ __forceinline__ float cc2(float x) {
    return ((-0.75f * x + 3.75f) * x - 6.0f) * x + 3.0f;
}

__device__ __forceinline__ void axis64(int o, float w[4], int idx[4]) {
    float src = (float)o * 63.0f / 255.0f;
    float f = floorf(src);
    float t = src - f;
    w[0] = cc2(t + 1.0f);
    w[1] = cc1(t);
    w[2] = cc1(1.0f - t);
    w[3] = cc2(2.0f - t);
    int i0 = (int)f;
#pragma unroll
    for (int k = 0; k < 4; ++k) idx[k] = min(max(i0 - 1 + k, 0), 63);
}

// Flow-warped sample weights/taps for output pixel (i,j), batch b.
// Partial-OOB taps get weight 0; returns false iff the whole 4x4 footprint
// is outside the padded [0,306) domain (then ALL weights are 0).
__device__ __forceinline__ bool pixel_taps(const float* __restrict__ flow, int b,
                                           int i, int j,
                                           float wx[4], float wy[4],
                                           int xs[4], int ys[4]) {
    float wwy[4], wwx[4];
    int yi4[4], xi4[4];
    axis64(i, wwy, yi4);
    axis64(j, wwx, xi4);

    const float* fb = flow + (long)b * 2 * 4096;
    float fx = 0.f, fy = 0.f;
#pragma unroll
    for (int m = 0; m < 4; ++m) {
        const float* r0 = fb + yi4[m] * 64;
        float sx = 0.f, sy = 0.f;
#pragma unroll
        for (int n = 0; n < 4; ++n) {
            sx += wwx[n] * r0[xi4[n]];
            sy += wwx[n] * r0[4096 + xi4[n]];
        }
        fx += wwy[m] * sx;
        fy += wwy[m] * sy;
    }

    const float gx256 = -1.0f + 2.0f * (float)j / 255.0f;
    const float gy256 = -1.0f + 2.0f * (float)i / 255.0f;
    const float gx306 = -1.0f + 2.0f * (float)(j + 25) / 305.0f;
    const float gy306 = -1.0f + 2.0f * (float)(i + 25) / 305.0f;
    const float x = (fx - gx256 + gx306 + 1.0f) * 152.5f;
    const float y = (fy - gy256 + gy306 + 1.0f) * 152.5f;

    const float ixf = floorf(x), iyf = floorf(y);
    const float tx = x - ixf, ty = y - iyf;
    wx[0] = cc2(tx + 1.f); wx[1] = cc1(tx); wx[2] = cc1(1.f - tx); wx[3] = cc2(2.f - tx);
    wy[0] = cc2(ty + 1.f); wy[1] = cc1(ty); wy[2] = cc1(1.f - ty); wy[3] = cc2(2.f - ty);
    const int ix = (int)ixf, iy = (int)iyf;

    bool anyx = false, anyy = false;
#pragma unroll
    for (int n = 0; n < 4; ++n) {
        int xx = ix - 1 + n;
        bool vx = (xx >= 0) && (xx < 306);
        anyx |= vx;
        if (!vx) wx[n] = 0.f;
        xs[n] = min(max(xx - 25, 0), 255);

        int yy = iy - 1 + n;
        bool vy = (yy >= 0) && (yy < 306);
        anyy |= vy;
        if (!vy) wy[n] = 0.f;
        ys[n] = min(max(yy - 25, 0), 255);
    }
    return anyx && anyy;
}

// ------- Kernel A: [B,C,H,W] fp32 -> ws [B,H*W,C] fp16 ----------------------
// Reads the full 268 MB input once -> HBM-roofline-bound (~48 us floor).
// Per-batch ws slice = 4 MB == one XCD's L2; b = blk&7 batch->XCD affinity.
__global__ __launch_bounds__(256) void transpose_clast_h_kernel(
    const float* __restrict__ inp, __half* __restrict__ ws)
{
    __shared__ float lds[32 * 260];
    const int blk = blockIdx.x;           // 2048
    const int b = blk & 7;                // XCD batch affinity
    const int p0 = (blk >> 3) << 8;       // 256-pixel tile
    const float* ib = inp + ((long)b << 21);
    const int tid = threadIdx.x;
    const int l = tid & 63;
    const int w = tid >> 6;

#pragma unroll
    for (int k = 0; k < 8; ++k) {
        const int c = (k << 2) + w;
        const float4 v = *(const float4*)(ib + ((long)c << 16) + p0 + (l << 2));
        *(float4*)&lds[c * 260 + (l << 2)] = v;
    }
    __syncthreads();

    // 16-B chunk f = q*256+tid of the block's 16-KB ws region:
    // pixel = f>>2, channel group = (f&3)*8 -> each wave-store 1 KB contiguous.
    __half* wsb = ws + (((long)b << 16) + p0) * 32;   // block base (fp16 elems)
#pragma unroll
    for (int q = 0; q < 4; ++q) {
        const int f  = (q << 8) + tid;
        const int px = f >> 2;
        const int c0 = (f & 3) << 3;
        __half2 h[4];
#pragma unroll
        for (int i = 0; i < 4; ++i) {
            float a  = lds[(c0 + 2 * i + 0) * 260 + px];
            float bb = lds[(c0 + 2 * i + 1) * 260 + px];
            h[i] = __float22half2_rn(make_float2(a, bb));
        }
        *(float4*)(wsb + ((long)f << 3)) = *(float4*)h;
    }
}

// ------- Kernel B: gather fp16 taps --------------------------------------
// v6: tap-split across waves. Block = 16 pixels; 256 thr = (px 0..15, g 0..3,
//     m 0..3): wave m handles tap-row m (4 taps) for all 16 px x 4 ch-groups.
//     Per-thread load chain is 4 (compiler issues all 4 -> real MLP), and
//     4x more waves per pixel give TLP latency hiding that rounds 2-4 proved
//     unreachable via per-lane registers (VGPR stuck at 36-52, 47-55 us).
//     Partial sums reduce across m-waves through LDS; wave 0 stores.
__global__ __launch_bounds__(256) void gather_clast_h_kernel(
    const __half* __restrict__ ws,   // [B, 65536, 32] fp16
    const float* __restrict__ flow,  // [B, 2, 64, 64]
    float* __restrict__ out)         // [B, 32, 256, 256] fp32
{
    __shared__ float w_lds[16][16];          // [tap k][px]
    __shared__ int   o_lds[16][16];          // [tap k][px]
    __shared__ int   v_lds[16];
    __shared__ float p_lds[4][4][8][16];     // [m][g][ch][px] partials, 8 KB

    const int tid = threadIdx.x;
    const int blk = blockIdx.x;          // 32768
    const int b = blk & 7;               // XCD batch affinity
    const int pidx0 = (blk >> 3) << 4;   // 16 pixels per block

    if (tid < 16) {
        const int pidx = pidx0 + tid;
        const int i = pidx >> 8, j = pidx & 255;
        float wx[4], wy[4];
        int xs[4], ys[4];
        const bool valid = pixel_taps(flow, b, i, j, wx, wy, xs, ys);
        v_lds[tid] = valid ? 1 : 0;
#pragma unroll
        for (int m = 0; m < 4; ++m)
#pragma unroll
            for (int n = 0; n < 4; ++n) {
                w_lds[m * 4 + n][tid] = wy[m] * wx[n];
                // offset in fp16 elements within the batch slice
                o_lds[m * 4 + n][tid] = (ys[m] << 13) + (xs[n] << 5);
            }
    }
    __syncthreads();

    const int m  = tid >> 6;             // wave = tap-row
    const int g  = tid & 3;              // channel group (adjacent lanes share tap line)
    const int px = (tid >> 2) & 15;      // local pixel

    float acc[8];
#pragma unroll
    for (int k = 0; k < 8; ++k) acc[k] = 0.f;

    if (v_lds[px]) {
        const __half* baseh = ws + ((long)b << 21) + (g << 3);
        float wr[4];
        float4 v[4];
#pragma unroll
        for (int n = 0; n < 4; ++n) wr[n] = w_lds[m * 4 + n][px];
#pragma unroll
        for (int n = 0; n < 4; ++n)
            v[n] = *(const float4*)(baseh + o_lds[m * 4 + n][px]);
#pragma unroll
        for (int n = 0; n < 4; ++n) {
            const __half2* h = (const __half2*)&v[n];
            const float w = wr[n];
#pragma unroll
            for (int q = 0; q < 4; ++q) {
                float2 f = __half22float2(h[q]);
                acc[2 * q + 0] += w * f.x;
                acc[2 * q + 1] += w * f.y;
            }
        }
    }

    // write partials (always: invalid px must contribute zeros)
#pragma unroll
    for (int k = 0; k < 8; ++k) p_lds[m][g][k][px] = acc[k];
    __syncthreads();

    if (tid < 64) {
        const int g2  = tid & 3;
        const int px2 = tid >> 2;
        float o8[8];
#pragma unroll
        for (int k = 0; k < 8; ++k)
            o8[k] = p_lds[0][g2][k][px2] + p_lds[1][g2][k][px2] +
                    p_lds[2][g2][k][px2] + p_lds[3][g2][k][px2];
        const int pidx = pidx0 + px2;
        float* op = out + ((long)b << 21) + ((long)(g2 << 3) << 16) + pidx;
#pragma unroll
        for (int k = 0; k < 8; ++k)
            op[(long)k << 16] = o8[k];
    }
}

// ---------------- Fallback if ws too small ----------------
__global__ __launch_bounds__(256) void warp_bicubic_fallback(
    const float* __restrict__ inp,
    const float* __restrict__ flow,
    float* __restrict__ out)
{
    const int j = threadIdx.x;
    const int i = blockIdx.x & 255;
    const int b = blockIdx.x >> 8;

    float wx[4], wy[4];
    int xs[4], ys[4];
    pixel_taps(flow, b, i, j, wx, wy, xs, ys);

    float* op = out + (long)b * 32 * 65536 + i * 256 + j;
    const float* ib = inp + (long)b * 32 * 65536;
#pragma unroll 2
    for (int c = 0; c < 32; ++c) {
        const float* s = ib + c * 65536;
        float acc = 0.f;
#pragma unroll
        for (int m = 0; m < 4; ++m) {
            float wm = wy[m];
            if (wm != 0.f) {
                const float* r = s + ys[m] * 256;
                acc += wm * (wx[0] * r[xs[0]] + wx[1] * r[xs[1]] +
                             wx[2] * r[xs[2]] + wx[3] * r[xs[3]]);
            }
        }
        op[c * 65536] = acc;
    }
}

extern "C" void kernel_launch(void* const* d_in, const int* in_sizes, int n_in,
                              void* d_out, int out_size, void* d_ws, size_t ws_size,
                              hipStream_t stream) {
    const float* inp  = (const float*)d_in[0];   // [8,32,256,256]
    const float* flow = (const float*)d_in[1];   // [8,2,64,64]
    float* out = (float*)d_out;

    const size_t need = (size_t)8 * 32 * 256 * 256 * sizeof(__half);  // 32 MiB
    if (ws_size >= need) {
        __half* ws = (__half*)d_ws;
        transpose_clast_h_kernel<<<dim3(2048), dim3(256), 0, stream>>>(inp, ws);
        gather_clast_h_kernel<<<dim3(32768), dim3(256), 0, stream>>>(ws, flow, out);
    } else {
        warp_bicubic_fallback<<<dim3(8 * 256), dim3(256), 0, stream>>>(inp, flow, out);
    }
}

// Round 7
// 145.686 us; speedup vs baseline: 1.1401x; 1.1401x over previous
//
#include <hip/hip_runtime.h>
#include <hip/hip_fp16.h>

// ---------------- bicubic helpers (A = -0.75, torch) ----------------
__device__ __forceinline__ float cc1(float x) {
    return (1.25f * x - 2.25f) * x * x + 1.0f;
}
__device__ __forceinline__ float cc2(float x) {
    return ((-0.75f * x + 3.75f) * x - 6.0f) * x + 3.0f;
}

__device__ __forceinline__ void axis64(int o, float w[4], int idx[4]) {
    float src = (float)o * 63.0f / 255.0f;
    float f = floorf(src);
    float t = src - f;
    w[0] = cc2(t + 1.0f);
    w[1] = cc1(t);
    w[2] = cc1(1.0f - t);
    w[3] = cc2(2.0f - t);
    int i0 = (int)f;
#pragma unroll
    for (int k = 0; k < 4; ++k) idx[k] = min(max(i0 - 1 + k, 0), 63);
}

// Flow-warped sample weights/taps for output pixel (i,j), batch b.
// Partial-OOB taps get weight 0; returns false iff the whole 4x4 footprint
// is outside the padded [0,306) domain (then ALL weights are 0).
__device__ __forceinline__ bool pixel_taps(const float* __restrict__ flow, int b,
                                           int i, int j,
                                           float wx[4], float wy[4],
                                           int xs[4], int ys[4]) {
    float wwy[4], wwx[4];
    int yi4[4], xi4[4];
    axis64(i, wwy, yi4);
    axis64(j, wwx, xi4);

    const float* fb = flow + (long)b * 2 * 4096;
    float fx = 0.f, fy = 0.f;
#pragma unroll
    for (int m = 0; m < 4; ++m) {
        const float* r0 = fb + yi4[m] * 64;
        float sx = 0.f, sy = 0.f;
#pragma unroll
        for (int n = 0; n < 4; ++n) {
            sx += wwx[n] * r0[xi4[n]];
            sy += wwx[n] * r0[4096 + xi4[n]];
        }
        fx += wwy[m] * sx;
        fy += wwy[m] * sy;
    }

    const float gx256 = -1.0f + 2.0f * (float)j / 255.0f;
    const float gy256 = -1.0f + 2.0f * (float)i / 255.0f;
    const float gx306 = -1.0f + 2.0f * (float)(j + 25) / 305.0f;
    const float gy306 = -1.0f + 2.0f * (float)(i + 25) / 305.0f;
    const float x = (fx - gx256 + gx306 + 1.0f) * 152.5f;
    const float y = (fy - gy256 + gy306 + 1.0f) * 152.5f;

    const float ixf = floorf(x), iyf = floorf(y);
    const float tx = x - ixf, ty = y - iyf;
    wx[0] = cc2(tx + 1.f); wx[1] = cc1(tx); wx[2] = cc1(1.f - tx); wx[3] = cc2(2.f - tx);
    wy[0] = cc2(ty + 1.f); wy[1] = cc1(ty); wy[2] = cc1(1.f - ty); wy[3] = cc2(2.f - ty);
    const int ix = (int)ixf, iy = (int)iyf;

    bool anyx = false, anyy = false;
#pragma unroll
    for (int n = 0; n < 4; ++n) {
        int xx = ix - 1 + n;
        bool vx = (xx >= 0) && (xx < 306);
        anyx |= vx;
        if (!vx) wx[n] = 0.f;
        xs[n] = min(max(xx - 25, 0), 255);

        int yy = iy - 1 + n;
        bool vy = (yy >= 0) && (yy < 306);
        anyy |= vy;
        if (!vy) wy[n] = 0.f;
        ys[n] = min(max(yy - 25, 0), 255);
    }
    return anyx && anyy;
}

// ------- Kernel A: [B,C,H,W] fp32 -> ws [B,H*W,C] fp16 ----------------------
// Reads the full 268 MB input once -> HBM-roofline-bound (~48 us floor).
// Per-batch ws slice = 4 MB == one XCD's L2; b = blk&7 batch->XCD affinity.
__global__ __launch_bounds__(256) void transpose_clast_h_kernel(
    const float* __restrict__ inp, __half* __restrict__ ws)
{
    __shared__ float lds[32 * 260];
    const int blk = blockIdx.x;           // 2048
    const int b = blk & 7;                // XCD batch affinity
    const int p0 = (blk >> 3) << 8;       // 256-pixel tile
    const float* ib = inp + ((long)b << 21);
    const int tid = threadIdx.x;
    const int l = tid & 63;
    const int w = tid >> 6;

#pragma unroll
    for (int k = 0; k < 8; ++k) {
        const int c = (k << 2) + w;
        const float4 v = *(const float4*)(ib + ((long)c << 16) + p0 + (l << 2));
        *(float4*)&lds[c * 260 + (l << 2)] = v;
    }
    __syncthreads();

    // 16-B chunk f = q*256+tid of the block's 16-KB ws region:
    // pixel = f>>2, channel group = (f&3)*8 -> each wave-store 1 KB contiguous.
    __half* wsb = ws + (((long)b << 16) + p0) * 32;   // block base (fp16 elems)
#pragma unroll
    for (int q = 0; q < 4; ++q) {
        const int f  = (q << 8) + tid;
        const int px = f >> 2;
        const int c0 = (f & 3) << 3;
        __half2 h[4];
#pragma unroll
        for (int i = 0; i < 4; ++i) {
            float a  = lds[(c0 + 2 * i + 0) * 260 + px];
            float bb = lds[(c0 + 2 * i + 1) * 260 + px];
            h[i] = __float22half2_rn(make_float2(a, bb));
        }
        *(float4*)(wsb + ((long)f << 3)) = *(float4*)h;
    }
}

// ------- Kernel B: gather fp16 taps, 64 px/block ---------------------------
// v7: v2 structure (best measured 47.4 us) with ONE change: quad-adjacent
//     lane mapping for the loads. Old: the 4 lanes sharing a (pixel,tap)
//     64-B line were lanes {p,p+16,p+32,p+48} -> no coalescing -> 64 separate
//     16-B requests per wave-load -> request-rate bound (33.5M requests
//     ~ 52 us model ~ measured 47-50; MLP attempts v3/v4 couldn't help).
//     New: g = lane&3, px = lane>>2 -> quad reads one contiguous 64-B line ->
//     4x fewer requests. Store side re-staged through padded LDS (<=2-way
//     banks, free) to keep v2's coalesced global-store pattern.
__global__ __launch_bounds__(256, 4) void gather_clast_h_kernel(
    const __half* __restrict__ ws,   // [B, 65536, 32] fp16
    const float* __restrict__ flow,  // [B, 2, 64, 64]
    float* __restrict__ out)         // [B, 32, 256, 256] fp32
{
    __shared__ float w_lds[16][64];
    __shared__ int   o_lds[16][64];
    __shared__ int   v_lds[64];
    __shared__ float p_lds[4][8][65];    // [g][ch][px] staged results, 8.3 KB

    const int tid = threadIdx.x;
    const int blk = blockIdx.x;      // 8192
    const int b = blk & 7;           // XCD batch affinity
    const int pidx0 = (blk >> 3) << 6;   // 64 pixels per block

    if (tid < 64) {
        const int pidx = pidx0 + tid;
        const int i = pidx >> 8, j = pidx & 255;
        float wx[4], wy[4];
        int xs[4], ys[4];
        const bool valid = pixel_taps(flow, b, i, j, wx, wy, xs, ys);
        v_lds[tid] = valid ? 1 : 0;
#pragma unroll
        for (int m = 0; m < 4; ++m)
#pragma unroll
            for (int n = 0; n < 4; ++n) {
                w_lds[m * 4 + n][tid] = wy[m] * wx[n];
                // offset in fp16 elements within the batch slice
                o_lds[m * 4 + n][tid] = (ys[m] << 13) + (xs[n] << 5);
            }
    }
    __syncthreads();

    const int lane = tid & 63;
    const int wv   = tid >> 6;               // wave 0..3
    const int g    = lane & 3;               // channel group: quad-adjacent!
    const int pl   = (wv << 4) + (lane >> 2); // local pixel 0..63

    const __half* baseh = ws + ((long)b << 21) + (g << 3);

    float acc[8];
#pragma unroll
    for (int k = 0; k < 8; ++k) acc[k] = 0.f;

    if (v_lds[pl]) {
        // v2's per-iteration load+FMA form (measured best); quad lanes now
        // cover one contiguous 64-B line -> hardware merges the requests.
#pragma unroll
        for (int k = 0; k < 16; ++k) {
            float4 v = *(const float4*)(baseh + o_lds[k][pl]);  // 8 fp16 ch
            const float w = w_lds[k][pl];
            const __half2* h = (const __half2*)&v;
#pragma unroll
            for (int m = 0; m < 4; ++m) {
                float2 f = __half22float2(h[m]);
                acc[2 * m + 0] += w * f.x;
                acc[2 * m + 1] += w * f.y;
            }
        }
    }

    // stage through LDS so global stores keep the v2 coalesced mapping
#pragma unroll
    for (int k = 0; k < 8; ++k) p_lds[g][k][pl] = acc[k];
    __syncthreads();

    const int g2  = lane >> 4;                // store mapping (v2): adjacent
    const int pl2 = (wv << 4) + (lane & 15);  // lanes = consecutive pixels
    const int pidx = pidx0 + pl2;
    float* op = out + ((long)b << 21) + ((long)(g2 << 3) << 16) + pidx;
#pragma unroll
    for (int k = 0; k < 8; ++k)
        op[(long)k << 16] = p_lds[g2][k][pl2];
}

// ---------------- Fallback if ws too small ----------------
__global__ __launch_bounds__(256) void warp_bicubic_fallback(
    const float* __restrict__ inp,
    const float* __restrict__ flow,
    float* __restrict__ out)
{
    const int j = threadIdx.x;
    const int i = blockIdx.x & 255;
    const int b = blockIdx.x >> 8;

    float wx[4], wy[4];
    int xs[4], ys[4];
    pixel_taps(flow, b, i, j, wx, wy, xs, ys);

    float* op = out + (long)b * 32 * 65536 + i * 256 + j;
    const float* ib = inp + (long)b * 32 * 65536;
#pragma unroll 2
    for (int c = 0; c < 32; ++c) {
        const float* s = ib + c * 65536;
        float acc = 0.f;
#pragma unroll
        for (int m = 0; m < 4; ++m) {
            float wm = wy[m];
            if (wm != 0.f) {
                const float* r = s + ys[m] * 256;
                acc += wm * (wx[0] * r[xs[0]] + wx[1] * r[xs[1]] +
                             wx[2] * r[xs[2]] + wx[3] * r[xs[3]]);
            }
        }
        op[c * 65536] = acc;
    }
}

extern "C" void kernel_launch(void* const* d_in, const int* in_sizes, int n_in,
                              void* d_out, int out_size, void* d_ws, size_t ws_size,
                              hipStream_t stream) {
    const float* inp  = (const float*)d_in[0];   // [8,32,256,256]
    const float* flow = (const float*)d_in[1];   // [8,2,64,64]
    float* out = (float*)d_out;

    const size_t need = (size_t)8 * 32 * 256 * 256 * sizeof(__half);  // 32 MiB
    if (ws_size >= need) {
        __half* ws = (__half*)d_ws;
        transpose_clast_h_kernel<<<dim3(2048), dim3(256), 0, stream>>>(inp, ws);
        gather_clast_h_kernel<<<dim3(8192), dim3(256), 0, stream>>>(ws, flow, out);
    } else {
        warp_bicubic_fallback<<<dim3(8 * 256), dim3(256), 0, stream>>>(inp, flow, out);
    }
}

// Round 8
// 144.027 us; speedup vs baseline: 1.1532x; 1.0115x over previous
//
#include <hip/hip_runtime.h>
#include <hip/hip_fp16.h>

// ---------------- bicubic helpers (A = -0.75, torch) ----------------
__device__ __forceinline__ float cc1(float x) {
    return (1.25f * x - 2.25f) * x * x + 1.0f;
}
__device__ __forceinline__ float cc2(float x) {
    return ((-0.75f * x + 3.75f) * x - 6.0f) * x + 3.0f;
}

__device__ __forceinline__ void axis64(int o, float w[4], int idx[4]) {
    float src = (float)o * 63.0f / 255.0f;
    float f = floorf(src);
    float t = src - f;
    w[0] = cc2(t + 1.0f);
    w[1] = cc1(t);
    w[2] = cc1(1.0f - t);
    w[3] = cc2(2.0f - t);
    int i0 = (int)f;
#pragma unroll
    for (int k = 0; k < 4; ++k) idx[k] = min(max(i0 - 1 + k, 0), 63);
}

// Flow-warped sample weights/taps for output pixel (i,j), batch b.
// (used by the fallback path only; the main gather kernel inlines an
//  m-split version of this)
__device__ __forceinline__ bool pixel_taps(const float* __restrict__ flow, int b,
                                           int i, int j,
                                           float wx[4], float wy[4],
                                           int xs[4], int ys[4]) {
    float wwy[4], wwx[4];
    int yi4[4], xi4[4];
    axis64(i, wwy, yi4);
    axis64(j, wwx, xi4);

    const float* fb = flow + (long)b * 2 * 4096;
    float fx = 0.f, fy = 0.f;
#pragma unroll
    for (int m = 0; m < 4; ++m) {
        const float* r0 = fb + yi4[m] * 64;
        float sx = 0.f, sy = 0.f;
#pragma unroll
        for (int n = 0; n < 4; ++n) {
            sx += wwx[n] * r0[xi4[n]];
            sy += wwx[n] * r0[4096 + xi4[n]];
        }
        fx += wwy[m] * sx;
        fy += wwy[m] * sy;
    }

    const float gx256 = -1.0f + 2.0f * (float)j / 255.0f;
    const float gy256 = -1.0f + 2.0f * (float)i / 255.0f;
    const float gx306 = -1.0f + 2.0f * (float)(j + 25) / 305.0f;
    const float gy306 = -1.0f + 2.0f * (float)(i + 25) / 305.0f;
    const float x = (fx - gx256 + gx306 + 1.0f) * 152.5f;
    const float y = (fy - gy256 + gy306 + 1.0f) * 152.5f;

    const float ixf = floorf(x), iyf = floorf(y);
    const float tx = x - ixf, ty = y - iyf;
    wx[0] = cc2(tx + 1.f); wx[1] = cc1(tx); wx[2] = cc1(1.f - tx); wx[3] = cc2(2.f - tx);
    wy[0] = cc2(ty + 1.f); wy[1] = cc1(ty); wy[2] = cc1(1.f - ty); wy[3] = cc2(2.f - ty);
    const int ix = (int)ixf, iy = (int)iyf;

    bool anyx = false, anyy = false;
#pragma unroll
    for (int n = 0; n < 4; ++n) {
        int xx = ix - 1 + n;
        bool vx = (xx >= 0) && (xx < 306);
        anyx |= vx;
        if (!vx) wx[n] = 0.f;
        xs[n] = min(max(xx - 25, 0), 255);

        int yy = iy - 1 + n;
        bool vy = (yy >= 0) && (yy < 306);
        anyy |= vy;
        if (!vy) wy[n] = 0.f;
        ys[n] = min(max(yy - 25, 0), 255);
    }
    return anyx && anyy;
}

// ------- Kernel A: [B,C,H,W] fp32 -> ws [B,H*W,C] fp16 ----------------------
// Reads the full 268 MB input once -> HBM-roofline-bound (~48 us floor).
// Per-batch ws slice = 4 MB == one XCD's L2; b = blk&7 batch->XCD affinity.
__global__ __launch_bounds__(256) void transpose_clast_h_kernel(
    const float* __restrict__ inp, __half* __restrict__ ws)
{
    __shared__ float lds[32 * 260];
    const int blk = blockIdx.x;           // 2048
    const int b = blk & 7;                // XCD batch affinity
    const int p0 = (blk >> 3) << 8;       // 256-pixel tile
    const float* ib = inp + ((long)b << 21);
    const int tid = threadIdx.x;
    const int l = tid & 63;
    const int w = tid >> 6;

#pragma unroll
    for (int k = 0; k < 8; ++k) {
        const int c = (k << 2) + w;
        const float4 v = *(const float4*)(ib + ((long)c << 16) + p0 + (l << 2));
        *(float4*)&lds[c * 260 + (l << 2)] = v;
    }
    __syncthreads();

    // 16-B chunk f = q*256+tid of the block's 16-KB ws region:
    // pixel = f>>2, channel group = (f&3)*8 -> each wave-store 1 KB contiguous.
    __half* wsb = ws + (((long)b << 16) + p0) * 32;   // block base (fp16 elems)
#pragma unroll
    for (int q = 0; q < 4; ++q) {
        const int f  = (q << 8) + tid;
        const int px = f >> 2;
        const int c0 = (f & 3) << 3;
        __half2 h[4];
#pragma unroll
        for (int i = 0; i < 4; ++i) {
            float a  = lds[(c0 + 2 * i + 0) * 260 + px];
            float bb = lds[(c0 + 2 * i + 1) * 260 + px];
            h[i] = __float22half2_rn(make_float2(a, bb));
        }
        *(float4*)(wsb + ((long)f << 3)) = *(float4*)h;
    }
}

// ------- Kernel B: gather fp16 taps, 64 px/block ---------------------------
// v7 (kept): quad-adjacent load mapping (g=lane&3) -> 64-B line coalescing
//     (47.4 -> 42.0 us); padded-LDS re-stage keeps coalesced stores.
// v8: prologue parallelized across all 256 threads. Old: tid<64 ran the full
//     pixel_taps (32 scattered flow loads + ~300 VALU) while waves 1-3 idled
//     at the barrier. New: thread (px=tid&63, m=tid>>6) computes tap-row m of
//     the flow interpolation (8 loads, 1/4 the FMAs); (fx,fy) reduced across
//     the 4 waves via LDS; the cheap load-free coordinate/weight tail is
//     computed redundantly and each thread writes only its row's 4 entries.
__global__ __launch_bounds__(256, 4) void gather_clast_h_kernel(
    const __half* __restrict__ ws,   // [B, 65536, 32] fp16
    const float* __restrict__ flow,  // [B, 2, 64, 64]
    float* __restrict__ out)         // [B, 32, 256, 256] fp32
{
    __shared__ float w_lds[16][64];
    __shared__ int   o_lds[16][64];
    __shared__ int   v_lds[64];
    __shared__ float p_lds[4][8][65];    // [g][ch][px] staged results, 8.3 KB
    __shared__ float red[4][2][68];      // [m][fx/fy][px] prologue partials

    const int tid = threadIdx.x;
    const int blk = blockIdx.x;      // 8192
    const int b = blk & 7;           // XCD batch affinity
    const int pidx0 = (blk >> 3) << 6;   // 64 pixels per block

    // ---- m-split prologue: all 256 threads active ----
    {
        const int px = tid & 63;
        const int m  = tid >> 6;
        const int pidx = pidx0 + px;
        const int i = pidx >> 8, j = pidx & 255;

        float wwy[4], wwx[4];
        int yi4[4], xi4[4];
        axis64(i, wwy, yi4);
        axis64(j, wwx, xi4);

        const float* fb = flow + (long)b * 2 * 4096;
        const float* r0 = fb + yi4[m] * 64;
        float sx = 0.f, sy = 0.f;
#pragma unroll
        for (int n = 0; n < 4; ++n) {
            sx += wwx[n] * r0[xi4[n]];
            sy += wwx[n] * r0[4096 + xi4[n]];
        }
        red[m][0][px] = wwy[m] * sx;
        red[m][1][px] = wwy[m] * sy;
        __syncthreads();

        const float fx = red[0][0][px] + red[1][0][px] +
                         red[2][0][px] + red[3][0][px];
        const float fy = red[0][1][px] + red[1][1][px] +
                         red[2][1][px] + red[3][1][px];

        const float gx256 = -1.0f + 2.0f * (float)j / 255.0f;
        const float gy256 = -1.0f + 2.0f * (float)i / 255.0f;
        const float gx306 = -1.0f + 2.0f * (float)(j + 25) / 305.0f;
        const float gy306 = -1.0f + 2.0f * (float)(i + 25) / 305.0f;
        const float x = (fx - gx256 + gx306 + 1.0f) * 152.5f;
        const float y = (fy - gy256 + gy306 + 1.0f) * 152.5f;

        const float ixf = floorf(x), iyf = floorf(y);
        const float tx = x - ixf, ty = y - iyf;
        float wx[4], wy4[4];
        wx[0] = cc2(tx + 1.f); wx[1] = cc1(tx);
        wx[2] = cc1(1.f - tx); wx[3] = cc2(2.f - tx);
        wy4[0] = cc2(ty + 1.f); wy4[1] = cc1(ty);
        wy4[2] = cc1(1.f - ty); wy4[3] = cc2(2.f - ty);
        const int ix = (int)ixf, iy = (int)iyf;

        bool anyx = false, anyy = false;
        int xs4[4];
#pragma unroll
        for (int n = 0; n < 4; ++n) {
            int xx = ix - 1 + n;
            bool vx = (xx >= 0) && (xx < 306);
            anyx |= vx;
            if (!vx) wx[n] = 0.f;
            xs4[n] = min(max(xx - 25, 0), 255);

            int yy = iy - 1 + n;
            anyy |= (yy >= 0) && (yy < 306);
        }
        // row m only
        const int yym = iy - 1 + m;
        const bool vym = (yym >= 0) && (yym < 306);
        const float wym = vym ? wy4[m] : 0.f;
        const int ysm = min(max(yym - 25, 0), 255);
#pragma unroll
        for (int n = 0; n < 4; ++n) {
            w_lds[m * 4 + n][px] = wym * wx[n];
            o_lds[m * 4 + n][px] = (ysm << 13) + (xs4[n] << 5);
        }
        if (m == 0) v_lds[px] = (anyx && anyy) ? 1 : 0;
    }
    __syncthreads();

    const int lane = tid & 63;
    const int wv   = tid >> 6;               // wave 0..3
    const int g    = lane & 3;               // channel group: quad-adjacent!
    const int pl   = (wv << 4) + (lane >> 2); // local pixel 0..63

    const __half* baseh = ws + ((long)b << 21) + (g << 3);

    float acc[8];
#pragma unroll
    for (int k = 0; k < 8; ++k) acc[k] = 0.f;

    if (v_lds[pl]) {
        // v2's per-iteration load+FMA form; quad lanes cover one contiguous
        // 64-B line -> hardware merges the requests (v7, proven).
#pragma unroll
        for (int k = 0; k < 16; ++k) {
            float4 v = *(const float4*)(baseh + o_lds[k][pl]);  // 8 fp16 ch
            const float w = w_lds[k][pl];
            const __half2* h = (const __half2*)&v;
#pragma unroll
            for (int m = 0; m < 4; ++m) {
                float2 f = __half22float2(h[m]);
                acc[2 * m + 0] += w * f.x;
                acc[2 * m + 1] += w * f.y;
            }
        }
    }

    // stage through LDS so global stores keep the v2 coalesced mapping
#pragma unroll
    for (int k = 0; k < 8; ++k) p_lds[g][k][pl] = acc[k];
    __syncthreads();

    const int g2  = lane >> 4;                // store mapping (v2): adjacent
    const int pl2 = (wv << 4) + (lane & 15);  // lanes = consecutive pixels
    const int pidx = pidx0 + pl2;
    float* op = out + ((long)b << 21) + ((long)(g2 << 3) << 16) + pidx;
#pragma unroll
    for (int k = 0; k < 8; ++k)
        op[(long)k << 16] = p_lds[g2][k][pl2];
}

// ---------------- Fallback if ws too small ----------------
__global__ __launch_bounds__(256) void warp_bicubic_fallback(
    const float* __restrict__ inp,
    const float* __restrict__ flow,
    float* __restrict__ out)
{
    const int j = threadIdx.x;
    const int i = blockIdx.x & 255;
    const int b = blockIdx.x >> 8;

    float wx[4], wy[4];
    int xs[4], ys[4];
    pixel_taps(flow, b, i, j, wx, wy, xs, ys);

    float* op = out + (long)b * 32 * 65536 + i * 256 + j;
    const float* ib = inp + (long)b * 32 * 65536;
#pragma unroll 2
    for (int c = 0; c < 32; ++c) {
        const float* s = ib + c * 65536;
        float acc = 0.f;
#pragma unroll
        for (int m = 0; m < 4; ++m) {
            float wm = wy[m];
            if (wm != 0.f) {
                const float* r = s + ys[m] * 256;
                acc += wm * (wx[0] * r[xs[0]] + wx[1] * r[xs[1]] +
                             wx[2] * r[xs[2]] + wx[3] * r[xs[3]]);
            }
        }
        op[c * 65536] = acc;
    }
}

extern "C" void kernel_launch(void* const* d_in, const int* in_sizes, int n_in,
                              void* d_out, int out_size, void* d_ws, size_t ws_size,
                              hipStream_t stream) {
    const float* inp  = (const float*)d_in[0];   // [8,32,256,256]
    const float* flow = (const float*)d_in[1];   // [8,2,64,64]
    float* out = (float*)d_out;

    const size_t need = (size_t)8 * 32 * 256 * 256 * sizeof(__half);  // 32 MiB
    if (ws_size >= need) {
        __half* ws = (__half*)d_ws;
        transpose_clast_h_kernel<<<dim3(2048), dim3(256), 0, stream>>>(inp, ws);
        gather_clast_h_kernel<<<dim3(8192), dim3(256), 0, stream>>>(ws, flow, out);
    } else {
        warp_bicubic_fallback<<<dim3(8 * 256), dim3(256), 0, stream>>>(inp, flow, out);
    }
}

// Round 9
// 142.913 us; speedup vs baseline: 1.1622x; 1.0078x over previous
//
#include <hip/hip_runtime.h>
#include <hip/hip_fp16.h>

// ---------------- bicubic helpers (A = -0.75, torch) ----------------
__device__ __forceinline__ float cc1(float x) {
    return (1.25f * x - 2.25f) * x * x + 1.0f;
}
__device__ __forceinline__ float cc2(float x) {
    return ((-0.75f * x + 3.75f) * x - 6.0f) * x + 3.0f;
}

__device__ __forceinline__ void axis64(int o, float w[4], int idx[4]) {
    float src = (float)o * 63.0f / 255.0f;
    float f = floorf(src);
    float t = src - f;
    w[0] = cc2(t + 1.0f);
    w[1] = cc1(t);
    w[2] = cc1(1.0f - t);
    w[3] = cc2(2.0f - t);
    int i0 = (int)f;
#pragma unroll
    for (int k = 0; k < 4; ++k) idx[k] = min(max(i0 - 1 + k, 0), 63);
}

// Flow-warped sample weights/taps for output pixel (i,j), batch b.
// (used by the fallback path only; the main gather kernel inlines an
//  m-split version of this)
__device__ __forceinline__ bool pixel_taps(const float* __restrict__ flow, int b,
                                           int i, int j,
                                           float wx[4], float wy[4],
                                           int xs[4], int ys[4]) {
    float wwy[4], wwx[4];
    int yi4[4], xi4[4];
    axis64(i, wwy, yi4);
    axis64(j, wwx, xi4);

    const float* fb = flow + (long)b * 2 * 4096;
    float fx = 0.f, fy = 0.f;
#pragma unroll
    for (int m = 0; m < 4; ++m) {
        const float* r0 = fb + yi4[m] * 64;
        float sx = 0.f, sy = 0.f;
#pragma unroll
        for (int n = 0; n < 4; ++n) {
            sx += wwx[n] * r0[xi4[n]];
            sy += wwx[n] * r0[4096 + xi4[n]];
        }
        fx += wwy[m] * sx;
        fy += wwy[m] * sy;
    }

    const float gx256 = -1.0f + 2.0f * (float)j / 255.0f;
    const float gy256 = -1.0f + 2.0f * (float)i / 255.0f;
    const float gx306 = -1.0f + 2.0f * (float)(j + 25) / 305.0f;
    const float gy306 = -1.0f + 2.0f * (float)(i + 25) / 305.0f;
    const float x = (fx - gx256 + gx306 + 1.0f) * 152.5f;
    const float y = (fy - gy256 + gy306 + 1.0f) * 152.5f;

    const float ixf = floorf(x), iyf = floorf(y);
    const float tx = x - ixf, ty = y - iyf;
    wx[0] = cc2(tx + 1.f); wx[1] = cc1(tx); wx[2] = cc1(1.f - tx); wx[3] = cc2(2.f - tx);
    wy[0] = cc2(ty + 1.f); wy[1] = cc1(ty); wy[2] = cc1(1.f - ty); wy[3] = cc2(2.f - ty);
    const int ix = (int)ixf, iy = (int)iyf;

    bool anyx = false, anyy = false;
#pragma unroll
    for (int n = 0; n < 4; ++n) {
        int xx = ix - 1 + n;
        bool vx = (xx >= 0) && (xx < 306);
        anyx |= vx;
        if (!vx) wx[n] = 0.f;
        xs[n] = min(max(xx - 25, 0), 255);

        int yy = iy - 1 + n;
        bool vy = (yy >= 0) && (yy < 306);
        anyy |= vy;
        if (!vy) wy[n] = 0.f;
        ys[n] = min(max(yy - 25, 0), 255);
    }
    return anyx && anyy;
}

// ------- Kernel A: [B,C,H,W] fp32 -> ws [B,H*W,C] fp16 ----------------------
// Reads the full 268 MB input once -> HBM-roofline-bound (~48 us floor).
// Per-batch ws slice = 4 MB == one XCD's L2; b = blk&7 batch->XCD affinity.
__global__ __launch_bounds__(256) void transpose_clast_h_kernel(
    const float* __restrict__ inp, __half* __restrict__ ws)
{
    __shared__ float lds[32 * 260];
    const int blk = blockIdx.x;           // 2048
    const int b = blk & 7;                // XCD batch affinity
    const int p0 = (blk >> 3) << 8;       // 256-pixel tile
    const float* ib = inp + ((long)b << 21);
    const int tid = threadIdx.x;
    const int l = tid & 63;
    const int w = tid >> 6;

#pragma unroll
    for (int k = 0; k < 8; ++k) {
        const int c = (k << 2) + w;
        const float4 v = *(const float4*)(ib + ((long)c << 16) + p0 + (l << 2));
        *(float4*)&lds[c * 260 + (l << 2)] = v;
    }
    __syncthreads();

    // 16-B chunk f = q*256+tid of the block's 16-KB ws region:
    // pixel = f>>2, channel group = (f&3)*8 -> each wave-store 1 KB contiguous.
    __half* wsb = ws + (((long)b << 16) + p0) * 32;   // block base (fp16 elems)
#pragma unroll
    for (int q = 0; q < 4; ++q) {
        const int f  = (q << 8) + tid;
        const int px = f >> 2;
        const int c0 = (f & 3) << 3;
        __half2 h[4];
#pragma unroll
        for (int i = 0; i < 4; ++i) {
            float a  = lds[(c0 + 2 * i + 0) * 260 + px];
            float bb = lds[(c0 + 2 * i + 1) * 260 + px];
            h[i] = __float22half2_rn(make_float2(a, bb));
        }
        *(float4*)(wsb + ((long)f << 3)) = *(float4*)h;
    }
}

// ------- Kernel B: gather fp16 taps, 64 px/block ---------------------------
// v7 (kept): quad-adjacent load mapping (g=lane&3) -> 64-B line coalescing.
// v8 (kept): m-split prologue across all 256 threads.
// v9: inner loop is VALU-issue-bound (VALUBusy 75%). Replace each tap's
//     8x v_cvt_f32_f16 + 8x v_fma_f32 with 8x v_fma_mix_f32 (f16 source
//     half consumed directly by an f32 FMA -- bit-identical result, ~40%
//     fewer inner VALU ops). Register-only asm with data-dep constraints:
//     loads stay compiler-scheduled (no v4-style pinning pathology).
__global__ __launch_bounds__(256, 4) void gather_clast_h_kernel(
    const __half* __restrict__ ws,   // [B, 65536, 32] fp16
    const float* __restrict__ flow,  // [B, 2, 64, 64]
    float* __restrict__ out)         // [B, 32, 256, 256] fp32
{
    __shared__ float w_lds[16][64];
    __shared__ int   o_lds[16][64];
    __shared__ int   v_lds[64];
    __shared__ float p_lds[4][8][65];    // [g][ch][px] staged results, 8.3 KB
    __shared__ float red[4][2][68];      // [m][fx/fy][px] prologue partials

    const int tid = threadIdx.x;
    const int blk = blockIdx.x;      // 8192
    const int b = blk & 7;           // XCD batch affinity
    const int pidx0 = (blk >> 3) << 6;   // 64 pixels per block

    // ---- m-split prologue: all 256 threads active ----
    {
        const int px = tid & 63;
        const int m  = tid >> 6;
        const int pidx = pidx0 + px;
        const int i = pidx >> 8, j = pidx & 255;

        float wwy[4], wwx[4];
        int yi4[4], xi4[4];
        axis64(i, wwy, yi4);
        axis64(j, wwx, xi4);

        const float* fb = flow + (long)b * 2 * 4096;
        const float* r0 = fb + yi4[m] * 64;
        float sx = 0.f, sy = 0.f;
#pragma unroll
        for (int n = 0; n < 4; ++n) {
            sx += wwx[n] * r0[xi4[n]];
            sy += wwx[n] * r0[4096 + xi4[n]];
        }
        red[m][0][px] = wwy[m] * sx;
        red[m][1][px] = wwy[m] * sy;
        __syncthreads();

        const float fx = red[0][0][px] + red[1][0][px] +
                         red[2][0][px] + red[3][0][px];
        const float fy = red[0][1][px] + red[1][1][px] +
                         red[2][1][px] + red[3][1][px];

        const float gx256 = -1.0f + 2.0f * (float)j / 255.0f;
        const float gy256 = -1.0f + 2.0f * (float)i / 255.0f;
        const float gx306 = -1.0f + 2.0f * (float)(j + 25) / 305.0f;
        const float gy306 = -1.0f + 2.0f * (float)(i + 25) / 305.0f;
        const float x = (fx - gx256 + gx306 + 1.0f) * 152.5f;
        const float y = (fy - gy256 + gy306 + 1.0f) * 152.5f;

        const float ixf = floorf(x), iyf = floorf(y);
        const float tx = x - ixf, ty = y - iyf;
        float wx[4], wy4[4];
        wx[0] = cc2(tx + 1.f); wx[1] = cc1(tx);
        wx[2] = cc1(1.f - tx); wx[3] = cc2(2.f - tx);
        wy4[0] = cc2(ty + 1.f); wy4[1] = cc1(ty);
        wy4[2] = cc1(1.f - ty); wy4[3] = cc2(2.f - ty);
        const int ix = (int)ixf, iy = (int)iyf;

        bool anyx = false, anyy = false;
        int xs4[4];
#pragma unroll
        for (int n = 0; n < 4; ++n) {
            int xx = ix - 1 + n;
            bool vx = (xx >= 0) && (xx < 306);
            anyx |= vx;
            if (!vx) wx[n] = 0.f;
            xs4[n] = min(max(xx - 25, 0), 255);

            int yy = iy - 1 + n;
            anyy |= (yy >= 0) && (yy < 306);
        }
        // row m only
        const int yym = iy - 1 + m;
        const bool vym = (yym >= 0) && (yym < 306);
        const float wym = vym ? wy4[m] : 0.f;
        const int ysm = min(max(yym - 25, 0), 255);
#pragma unroll
        for (int n = 0; n < 4; ++n) {
            w_lds[m * 4 + n][px] = wym * wx[n];
            o_lds[m * 4 + n][px] = (ysm << 13) + (xs4[n] << 5);
        }
        if (m == 0) v_lds[px] = (anyx && anyy) ? 1 : 0;
    }
    __syncthreads();

    const int lane = tid & 63;
    const int wv   = tid >> 6;               // wave 0..3
    const int g    = lane & 3;               // channel group: quad-adjacent!
    const int pl   = (wv << 4) + (lane >> 2); // local pixel 0..63

    const __half* baseh = ws + ((long)b << 21) + (g << 3);

    float acc[8];
#pragma unroll
    for (int k = 0; k < 8; ++k) acc[k] = 0.f;

    if (v_lds[pl]) {
#pragma unroll
        for (int k = 0; k < 16; ++k) {
            uint4 v = *(const uint4*)(baseh + o_lds[k][pl]);  // 8 fp16 ch
            const float w = w_lds[k][pl];
            // acc[2q]   += f32(lo_half(v[q])) * w
            // acc[2q+1] += f32(hi_half(v[q])) * w   (v_fma_mix_f32, exact)
#pragma unroll
            for (int q = 0; q < 4; ++q) {
                const unsigned hv = (&v.x)[q];
                asm("v_fma_mix_f32 %0, %1, %2, %0 op_sel:[0,0,0] op_sel_hi:[1,0,0]"
                    : "+v"(acc[2 * q + 0]) : "v"(hv), "v"(w));
                asm("v_fma_mix_f32 %0, %1, %2, %0 op_sel:[1,0,0] op_sel_hi:[1,0,0]"
                    : "+v"(acc[2 * q + 1]) : "v"(hv), "v"(w));
            }
        }
    }

    // stage through LDS so global stores keep the v2 coalesced mapping
#pragma unroll
    for (int k = 0; k < 8; ++k) p_lds[g][k][pl] = acc[k];
    __syncthreads();

    const int g2  = lane >> 4;                // store mapping (v2): adjacent
    const int pl2 = (wv << 4) + (lane & 15);  // lanes = consecutive pixels
    const int pidx = pidx0 + pl2;
    float* op = out + ((long)b << 21) + ((long)(g2 << 3) << 16) + pidx;
#pragma unroll
    for (int k = 0; k < 8; ++k)
        op[(long)k << 16] = p_lds[g2][k][pl2];
}

// ---------------- Fallback if ws too small ----------------
__global__ __launch_bounds__(256) void warp_bicubic_fallback(
    const float* __restrict__ inp,
    const float* __restrict__ flow,
    float* __restrict__ out)
{
    const int j = threadIdx.x;
    const int i = blockIdx.x & 255;
    const int b = blockIdx.x >> 8;

    float wx[4], wy[4];
    int xs[4], ys[4];
    pixel_taps(flow, b, i, j, wx, wy, xs, ys);

    float* op = out + (long)b * 32 * 65536 + i * 256 + j;
    const float* ib = inp + (long)b * 32 * 65536;
#pragma unroll 2
    for (int c = 0; c < 32; ++c) {
        const float* s = ib + c * 65536;
        float acc = 0.f;
#pragma unroll
        for (int m = 0; m < 4; ++m) {
            float wm = wy[m];
            if (wm != 0.f) {
                const float* r = s + ys[m] * 256;
                acc += wm * (wx[0] * r[xs[0]] + wx[1] * r[xs[1]] +
                             wx[2] * r[xs[2]] + wx[3] * r[xs[3]]);
            }
        }
        op[c * 65536] = acc;
    }
}

extern "C" void kernel_launch(void* const* d_in, const int* in_sizes, int n_in,
                              void* d_out, int out_size, void* d_ws, size_t ws_size,
                              hipStream_t stream) {
    const float* inp  = (const float*)d_in[0];   // [8,32,256,256]
    const float* flow = (const float*)d_in[1];   // [8,2,64,64]
    float* out = (float*)d_out;

    const size_t need = (size_t)8 * 32 * 256 * 256 * sizeof(__half);  // 32 MiB
    if (ws_size >= need) {
        __half* ws = (__half*)d_ws;
        transpose_clast_h_kernel<<<dim3(2048), dim3(256), 0, stream>>>(inp, ws);
        gather_clast_h_kernel<<<dim3(8192), dim3(256), 0, stream>>>(ws, flow, out);
    } else {
        warp_bicubic_fallback<<<dim3(8 * 256), dim3(256), 0, stream>>>(inp, flow, out);
    }
}

// Round 10
// 140.914 us; speedup vs baseline: 1.1787x; 1.0142x over previous
//
#include <hip/hip_runtime.h>
#include <hip/hip_fp16.h>

// ---------------- bicubic helpers (A = -0.75, torch) ----------------
__device__ __forceinline__ float cc1(float x) {
    return (1.25f * x - 2.25f) * x * x + 1.0f;
}
__device__ __forceinline__ float cc2(float x) {
    return ((-0.75f * x + 3.75f) * x - 6.0f) * x + 3.0f;
}

__device__ __forceinline__ void axis64(int o, float w[4], int idx[4]) {
    float src = (float)o * 63.0f / 255.0f;
    float f = floorf(src);
    float t = src - f;
    w[0] = cc2(t + 1.0f);
    w[1] = cc1(t);
    w[2] = cc1(1.0f - t);
    w[3] = cc2(2.0f - t);
    int i0 = (int)f;
#pragma unroll
    for (int k = 0; k < 4; ++k) idx[k] = min(max(i0 - 1 + k, 0), 63);
}

// Warped absolute sample coordinate (x,y) in the padded [0,306) domain for
// output pixel (i,j), batch b. Pure per-pixel function of flow.
__device__ __forceinline__ float2 warp_coord(const float* __restrict__ flow,
                                             int b, int i, int j) {
    float wwy[4], wwx[4];
    int yi4[4], xi4[4];
    axis64(i, wwy, yi4);
    axis64(j, wwx, xi4);

    const float* fb = flow + (long)b * 2 * 4096;
    float fx = 0.f, fy = 0.f;
#pragma unroll
    for (int m = 0; m < 4; ++m) {
        const float* r0 = fb + yi4[m] * 64;
        float sx = 0.f, sy = 0.f;
#pragma unroll
        for (int n = 0; n < 4; ++n) {
            sx += wwx[n] * r0[xi4[n]];
            sy += wwx[n] * r0[4096 + xi4[n]];
        }
        fx += wwy[m] * sx;
        fy += wwy[m] * sy;
    }

    const float gx256 = -1.0f + 2.0f * (float)j / 255.0f;
    const float gy256 = -1.0f + 2.0f * (float)i / 255.0f;
    const float gx306 = -1.0f + 2.0f * (float)(j + 25) / 305.0f;
    const float gy306 = -1.0f + 2.0f * (float)(i + 25) / 305.0f;
    const float x = (fx - gx256 + gx306 + 1.0f) * 152.5f;
    const float y = (fy - gy256 + gy306 + 1.0f) * 152.5f;
    return make_float2(x, y);
}

// Full taps (fallback path only)
__device__ __forceinline__ bool pixel_taps(const float* __restrict__ flow, int b,
                                           int i, int j,
                                           float wx[4], float wy[4],
                                           int xs[4], int ys[4]) {
    const float2 xy = warp_coord(flow, b, i, j);
    const float x = xy.x, y = xy.y;
    const float ixf = floorf(x), iyf = floorf(y);
    const float tx = x - ixf, ty = y - iyf;
    wx[0] = cc2(tx + 1.f); wx[1] = cc1(tx); wx[2] = cc1(1.f - tx); wx[3] = cc2(2.f - tx);
    wy[0] = cc2(ty + 1.f); wy[1] = cc1(ty); wy[2] = cc1(1.f - ty); wy[3] = cc2(2.f - ty);
    const int ix = (int)ixf, iy = (int)iyf;

    bool anyx = false, anyy = false;
#pragma unroll
    for (int n = 0; n < 4; ++n) {
        int xx = ix - 1 + n;
        bool vx = (xx >= 0) && (xx < 306);
        anyx |= vx;
        if (!vx) wx[n] = 0.f;
        xs[n] = min(max(xx - 25, 0), 255);

        int yy = iy - 1 + n;
        bool vy = (yy >= 0) && (yy < 306);
        anyy |= vy;
        if (!vy) wy[n] = 0.f;
        ys[n] = min(max(yy - 25, 0), 255);
    }
    return anyx && anyy;
}

// ------- Kernel A: transpose + coordinate precompute ------------------------
// [B,C,H,W] fp32 -> ws [B,H*W,C] fp16 (67 MB read + 34 MB write, HBM-bound
// ~16 us, VALUBusy ~5%) and, per thread (=1 pixel), the warped (x,y) coords
// into a float2 table (v10: hoists the flow interp out of the gather's
// per-block-redundant prologue into this kernel's idle VALU headroom).
__global__ __launch_bounds__(256) void transpose_clast_h_kernel(
    const float* __restrict__ inp, const float* __restrict__ flow,
    __half* __restrict__ ws, float2* __restrict__ coords)
{
    __shared__ float lds[32 * 260];
    const int blk = blockIdx.x;           // 2048
    const int b = blk & 7;                // XCD batch affinity
    const int p0 = (blk >> 3) << 8;       // 256-pixel tile
    const float* ib = inp + ((long)b << 21);
    const int tid = threadIdx.x;
    const int l = tid & 63;
    const int w = tid >> 6;

#pragma unroll
    for (int k = 0; k < 8; ++k) {
        const int c = (k << 2) + w;
        const float4 v = *(const float4*)(ib + ((long)c << 16) + p0 + (l << 2));
        *(float4*)&lds[c * 260 + (l << 2)] = v;
    }

    // coordinate precompute: independent of LDS, overlaps the barrier
    {
        const int pidx = p0 + tid;
        coords[((long)b << 16) + pidx] =
            warp_coord(flow, b, pidx >> 8, pidx & 255);
    }
    __syncthreads();

    // 16-B chunk f = q*256+tid of the block's 16-KB ws region:
    // pixel = f>>2, channel group = (f&3)*8 -> each wave-store 1 KB contiguous.
    __half* wsb = ws + (((long)b << 16) + p0) * 32;   // block base (fp16 elems)
#pragma unroll
    for (int q = 0; q < 4; ++q) {
        const int f  = (q << 8) + tid;
        const int px = f >> 2;
        const int c0 = (f & 3) << 3;
        __half2 h[4];
#pragma unroll
        for (int i = 0; i < 4; ++i) {
            float a  = lds[(c0 + 2 * i + 0) * 260 + px];
            float bb = lds[(c0 + 2 * i + 1) * 260 + px];
            h[i] = __float22half2_rn(make_float2(a, bb));
        }
        *(float4*)(wsb + ((long)f << 3)) = *(float4*)h;
    }
}

// ------- Kernel B: gather fp16 taps, 64 px/block ---------------------------
// v7 (kept): quad-adjacent load mapping (g=lane&3) -> 64-B line coalescing.
// v9 (kept): v_fma_mix_f32 inner loop (f16 source consumed by f32 FMA).
// v10: prologue reads precomputed (x,y) (8 B/px, coalesced, L2-hot) and keeps
//      only the weight/clamp tail (~80 ops vs ~200); drops the flow interp,
//      the red[] cross-wave reduction and one __syncthreads.
__global__ __launch_bounds__(256, 4) void gather_clast_h_kernel(
    const __half* __restrict__ ws,       // [B, 65536, 32] fp16
    const float2* __restrict__ coords,   // [B, 65536] warped (x,y)
    float* __restrict__ out)             // [B, 32, 256, 256] fp32
{
    __shared__ float w_lds[16][64];
    __shared__ int   o_lds[16][64];
    __shared__ int   v_lds[64];
    __shared__ float p_lds[4][8][65];    // [g][ch][px] staged results, 8.3 KB

    const int tid = threadIdx.x;
    const int blk = blockIdx.x;      // 8192
    const int b = blk & 7;           // XCD batch affinity
    const int pidx0 = (blk >> 3) << 6;   // 64 pixels per block

    // ---- m-split prologue: all 256 threads, no flow interp ----
    {
        const int px = tid & 63;
        const int m  = tid >> 6;
        const int pidx = pidx0 + px;

        const float2 xy = coords[((long)b << 16) + pidx];
        const float x = xy.x, y = xy.y;

        const float ixf = floorf(x), iyf = floorf(y);
        const float tx = x - ixf, ty = y - iyf;
        float wx[4], wy4[4];
        wx[0] = cc2(tx + 1.f); wx[1] = cc1(tx);
        wx[2] = cc1(1.f - tx); wx[3] = cc2(2.f - tx);
        wy4[0] = cc2(ty + 1.f); wy4[1] = cc1(ty);
        wy4[2] = cc1(1.f - ty); wy4[3] = cc2(2.f - ty);
        const int ix = (int)ixf, iy = (int)iyf;

        bool anyx = false, anyy = false;
        int xs4[4];
#pragma unroll
        for (int n = 0; n < 4; ++n) {
            int xx = ix - 1 + n;
            bool vx = (xx >= 0) && (xx < 306);
            anyx |= vx;
            if (!vx) wx[n] = 0.f;
            xs4[n] = min(max(xx - 25, 0), 255);

            int yy = iy - 1 + n;
            anyy |= (yy >= 0) && (yy < 306);
        }
        // row m only
        const int yym = iy - 1 + m;
        const bool vym = (yym >= 0) && (yym < 306);
        const float wym = vym ? wy4[m] : 0.f;
        const int ysm = min(max(yym - 25, 0), 255);
#pragma unroll
        for (int n = 0; n < 4; ++n) {
            w_lds[m * 4 + n][px] = wym * wx[n];
            o_lds[m * 4 + n][px] = (ysm << 13) + (xs4[n] << 5);
        }
        if (m == 0) v_lds[px] = (anyx && anyy) ? 1 : 0;
    }
    __syncthreads();

    const int lane = tid & 63;
    const int wv   = tid >> 6;               // wave 0..3
    const int g    = lane & 3;               // channel group: quad-adjacent!
    const int pl   = (wv << 4) + (lane >> 2); // local pixel 0..63

    const __half* baseh = ws + ((long)b << 21) + (g << 3);

    float acc[8];
#pragma unroll
    for (int k = 0; k < 8; ++k) acc[k] = 0.f;

    if (v_lds[pl]) {
#pragma unroll
        for (int k = 0; k < 16; ++k) {
            uint4 v = *(const uint4*)(baseh + o_lds[k][pl]);  // 8 fp16 ch
            const float w = w_lds[k][pl];
#pragma unroll
            for (int q = 0; q < 4; ++q) {
                const unsigned hv = (&v.x)[q];
                asm("v_fma_mix_f32 %0, %1, %2, %0 op_sel:[0,0,0] op_sel_hi:[1,0,0]"
                    : "+v"(acc[2 * q + 0]) : "v"(hv), "v"(w));
                asm("v_fma_mix_f32 %0, %1, %2, %0 op_sel:[1,0,0] op_sel_hi:[1,0,0]"
                    : "+v"(acc[2 * q + 1]) : "v"(hv), "v"(w));
            }
        }
    }

    // stage through LDS so global stores keep the v2 coalesced mapping
#pragma unroll
    for (int k = 0; k < 8; ++k) p_lds[g][k][pl] = acc[k];
    __syncthreads();

    const int g2  = lane >> 4;                // store mapping (v2): adjacent
    const int pl2 = (wv << 4) + (lane & 15);  // lanes = consecutive pixels
    const int pidx = pidx0 + pl2;
    float* op = out + ((long)b << 21) + ((long)(g2 << 3) << 16) + pidx;
#pragma unroll
    for (int k = 0; k < 8; ++k)
        op[(long)k << 16] = p_lds[g2][k][pl2];
}

// ---------------- Fallback if ws too small ----------------
__global__ __launch_bounds__(256) void warp_bicubic_fallback(
    const float* __restrict__ inp,
    const float* __restrict__ flow,
    float* __restrict__ out)
{
    const int j = threadIdx.x;
    const int i = blockIdx.x & 255;
    const int b = blockIdx.x >> 8;

    float wx[4], wy[4];
    int xs[4], ys[4];
    pixel_taps(flow, b, i, j, wx, wy, xs, ys);

    float* op = out + (long)b * 32 * 65536 + i * 256 + j;
    const float* ib = inp + (long)b * 32 * 65536;
#pragma unroll 2
    for (int c = 0; c < 32; ++c) {
        const float* s = ib + c * 65536;
        float acc = 0.f;
#pragma unroll
        for (int m = 0; m < 4; ++m) {
            float wm = wy[m];
            if (wm != 0.f) {
                const float* r = s + ys[m] * 256;
                acc += wm * (wx[0] * r[xs[0]] + wx[1] * r[xs[1]] +
                             wx[2] * r[xs[2]] + wx[3] * r[xs[3]]);
            }
        }
        op[c * 65536] = acc;
    }
}

extern "C" void kernel_launch(void* const* d_in, const int* in_sizes, int n_in,
                              void* d_out, int out_size, void* d_ws, size_t ws_size,
                              hipStream_t stream) {
    const float* inp  = (const float*)d_in[0];   // [8,32,256,256]
    const float* flow = (const float*)d_in[1];   // [8,2,64,64]
    float* out = (float*)d_out;

    const size_t half_bytes = (size_t)8 * 65536 * 32 * sizeof(__half);  // 32 MiB
    const size_t coord_bytes = (size_t)8 * 65536 * sizeof(float2);      // 4 MiB
    if (ws_size >= half_bytes + coord_bytes) {
        __half* ws = (__half*)d_ws;
        float2* coords = (float2*)((char*)d_ws + half_bytes);
        transpose_clast_h_kernel<<<dim3(2048), dim3(256), 0, stream>>>(inp, flow, ws, coords);
        gather_clast_h_kernel<<<dim3(8192), dim3(256), 0, stream>>>(ws, coords, out);
    } else {
        warp_bicubic_fallback<<<dim3(8 * 256), dim3(256), 0, stream>>>(inp, flow, out);
    }
}